// Round 19
// baseline (155.417 us; speedup 1.0000x reference)
//
#include <hip/hip_runtime.h>
#include <hip/hip_bf16.h>

// F2VConv3d: per-face double-GEMM (both on MFMA) then vertex gather + BN.
//   W[f,:] = fc[f,:] @ sw          (MFMA1, K=16 padded to 32, computed as W^T)
//   feat[f,cm] = inp[f,cm>>1] * W[f,cm]   (multiplier iv from REGISTERS)
//   g[f] = feat[f,:] @ dw          (MFMA2 swapped -> direct g stores)
//   out[v] = BN(relu(mean_{f in N(v)} g[f] + bias))
// R19: occupancy experiment. R11-R18 all land at 66-69us with clean counters
// regardless of barrier/staging structure -> latency-bound at 2 blocks/CU.
// Delete the DMA+double-buffer machinery entirely: iv multipliers loaded
// straight to registers (32 VGPR), LDS = single 32KB feat buffer, 2 barriers
// per tile, launch_bounds(256,3) + GRIDF=768 -> 3 blocks/CU (12 waves/CU).
// Register fit: invariant a1(16)+bfr(64)=80, peak ~156 < 170 cap.

constexpr int C_IN  = 128;
constexpr int KF    = 16;
constexpr int CM    = 256;    // C_IN * MULT
constexpr int C_OUT = 128;
constexpr int CAP   = 32;     // max tracked faces per vertex
constexpr int GB    = 1024;   // k_gather grid (k_red loops over GB)
constexpr int FT    = 64;     // faces per k_faceg tile
constexpr int GRIDF = 768;    // k_faceg grid (3 blocks/CU)
constexpr float BN_EPS = 1e-3f;

typedef __attribute__((ext_vector_type(8))) short short8;
typedef __attribute__((ext_vector_type(4))) float f32x4;

__device__ __forceinline__ ushort f2bf(float x) {
  union { float f; unsigned u; } v; v.f = x;
  return (ushort)((v.u + 0x7fffu + ((v.u >> 16) & 1u)) >> 16);
}
__device__ __forceinline__ float b2f(ushort u) {
  return __uint_as_float((unsigned)u << 16);
}
__device__ __forceinline__ uint pk2(float a, float b) {
  __hip_bfloat162 h = __float22bfloat162_rn(float2{a, b});
  return *(uint*)&h;
}
__device__ __forceinline__ void bar_lds() {
  asm volatile("s_waitcnt lgkmcnt(0)" ::: "memory");
  __builtin_amdgcn_s_barrier();
  asm volatile("" ::: "memory");
}

// Merged prep + fill. Blocks 0..95: dwt/swt transform. Blocks 96..: CSR fill.
__global__ __launch_bounds__(256) void k_prepfill(
    const float* __restrict__ dw, const float* __restrict__ sw,
    ushort* __restrict__ dwt, ushort* __restrict__ swt,
    const int* __restrict__ face, const int* __restrict__ vt_map,
    int* __restrict__ cnt, int* __restrict__ slots, int n_inc) {
  const int b = blockIdx.x, tid = threadIdx.x;
  if (b < 64) {                       // dwt: 128*256 elems, 2/thread
    int i = b * 512 + tid;
#pragma unroll
    for (int r = 0; r < 2; ++r, i += 256) {
      int n = i >> 8, k = i & 255;
      dwt[i] = f2bf(dw[k * C_OUT + n]);
    }
  } else if (b < 96) {                // swt: 256*32 elems, 1/thread
    int i = (b - 64) * 256 + tid;
    int cm = i >> 5, k = i & 31;
    swt[i] = (k < KF) ? f2bf(sw[k * CM + cm]) : (ushort)0;
  } else {                            // fill
    int i = (b - 96) * 256 + tid;
    if (i < n_inc) {
      int f = i / 3;
      int v = vt_map[face[i]];
      int p = atomicAdd(&cnt[v], 1);
      if (p < CAP) slots[(size_t)v * CAP + p] = f;
    }
  }
}

// Persistent k_faceg, no DMA: per tile [iv+fc reg loads] [TOP bar_lds]
// [b1] [MFMA1 + reg-multiply -> feat LDS write] [bar: feat ready]
// [MFMA2 swapped reading feat + direct g stores].  2 barriers/tile.
__global__ __launch_bounds__(256, 3) void k_faceg(
    const float* __restrict__ inp, const float* __restrict__ fc,
    const ushort* __restrict__ swt, const ushort* __restrict__ dwt,
    ushort* __restrict__ g, int ntiles) {
  __shared__ __align__(1024) ushort s_feat[FT * 256];   // 32768 B
  char* sb = (char*)s_feat;

  const int tid  = threadIdx.x;
  const int w    = tid >> 6;        // wave -> cm range [w*64, w*64+64)
  const int lane = tid & 63;
  const int rm   = lane & 15;
  const int kg   = lane >> 4;

  // loop-invariant fragments (~80 VGPR; (256,3) cap = 170)
  short8 a1[4];
#pragma unroll
  for (int ct = 0; ct < 4; ++ct)
    a1[ct] = *(const short8*)&swt[(size_t)(w * 64 + ct * 16 + rm) * 32 + kg * 8];
  short8 bfr[2][8];
#pragma unroll
  for (int nt = 0; nt < 2; ++nt) {
    const int n = (w * 2 + nt) * 16 + rm;
#pragma unroll
    for (int ks = 0; ks < 8; ++ks)
      bfr[nt][ks] = *(const short8*)&dwt[n * 256 + ks * 32 + kg * 8];
  }

  for (int t = blockIdx.x; t < ntiles; t += GRIDF) {
    const int fb = t * FT;

    // iv multipliers -> registers (32 VGPR), issued before the barrier so
    // their latency hides under the prev tile's MFMA2 drain.
    float2 iv[4][4];
#pragma unroll
    for (int ft = 0; ft < 4; ++ft) {
      const float* rowp = &inp[(size_t)(fb + ft * 16 + rm) * C_IN];
#pragma unroll
      for (int ct = 0; ct < 4; ++ct)
        iv[ft][ct] = *(const float2*)&rowp[(w * 16 + ct * 4 + kg) * 2];
    }
    // fc for MFMA1 B-operand
    float4 p0[4], p1[4];
#pragma unroll
    for (int ft = 0; ft < 4; ++ft) {
      const float* fr = &fc[(size_t)(fb + ft * 16 + rm) * KF + (kg & 1) * 8];
      p0[ft] = *(const float4*)fr;
      p1[ft] = *(const float4*)(fr + 4);
    }
    __builtin_amdgcn_sched_barrier(0);   // keep loads hoisted & live

    bar_lds();                        // TOP: prev tile's feat reads drained

    short8 b1[4];
#pragma unroll
    for (int ft = 0; ft < 4; ++ft) {
      uint4 u;
      u.x = pk2(p0[ft].x, p0[ft].y); u.y = pk2(p0[ft].z, p0[ft].w);
      u.z = pk2(p1[ft].x, p1[ft].y); u.w = pk2(p1[ft].z, p1[ft].w);
      if (kg >= 2) u = uint4{0, 0, 0, 0};   // K padded 16->32
      b1[ft] = *(short8*)&u;
    }

    // MFMA1 + register-multiply epilogue -> feat bf16 LDS write (no read!)
    // D layout (m89): col=rm -> face ft*16+rm, row=kg*4+r -> cm cmb+r
#pragma unroll
    for (int ft = 0; ft < 4; ++ft) {
#pragma unroll
      for (int ct = 0; ct < 4; ++ct) {
        f32x4 acc = {0.f, 0.f, 0.f, 0.f};
        acc = __builtin_amdgcn_mfma_f32_16x16x32_bf16(a1[ct], b1[ft], acc, 0, 0, 0);
        const int face = ft * 16 + rm;
        const int cmb  = w * 64 + ct * 16 + kg * 4;
        const int byt  = face * 512 + ((((cmb * 2) >> 4) ^ (face & 7)) << 4)
                       + ((cmb * 2) & 15);
        const float i0 = iv[ft][ct].x;    // channel cmb>>1
        const float i1 = iv[ft][ct].y;    // channel (cmb>>1)+1
        uint2 pw;
        pw.x = pk2(acc[0] * i0, acc[1] * i0);
        pw.y = pk2(acc[2] * i1, acc[3] * i1);
        *(uint2*)(sb + byt) = pw;
      }
    }

    bar_lds();                        // feat ready

    // MFMA2 with SWAPPED operands: D[row=channel][col=face]; lane rm = face,
    // channels (w*2+nt)*16+kg*4+r -> cvt_pk + direct 8B g stores.
    f32x4 acc2[4][2];
#pragma unroll
    for (int fs = 0; fs < 4; ++fs)
#pragma unroll
      for (int nt = 0; nt < 2; ++nt)
        acc2[fs][nt] = (f32x4){0.f, 0.f, 0.f, 0.f};

#pragma unroll
    for (int fs = 0; fs < 4; ++fs)
#pragma unroll
      for (int ks = 0; ks < 8; ++ks) {
        const int row = fs * 16 + rm;
        const int byt = row * 512 + (((ks * 4 + kg) ^ (row & 7)) << 4);
        const short8 af = *(const short8*)(sb + byt);
        acc2[fs][0] = __builtin_amdgcn_mfma_f32_16x16x32_bf16(bfr[0][ks], af, acc2[fs][0], 0, 0, 0);
        acc2[fs][1] = __builtin_amdgcn_mfma_f32_16x16x32_bf16(bfr[1][ks], af, acc2[fs][1], 0, 0, 0);
      }

#pragma unroll
    for (int fs = 0; fs < 4; ++fs) {
      const size_t rowoff = (size_t)(fb + fs * 16 + rm) * C_OUT;
#pragma unroll
      for (int nt = 0; nt < 2; ++nt) {
        uint2 pw;
        pw.x = pk2(acc2[fs][nt][0], acc2[fs][nt][1]);
        pw.y = pk2(acc2[fs][nt][2], acc2[fs][nt][3]);
        *(uint2*)&g[rowoff + (w * 2 + nt) * 16 + kg * 4] = pw;
      }
    }
  }
}

// 16 verts/tile, 16 threads/vert. Writes bf16 pre-BN buffer (half traffic);
// partials transposed part[col][GB]. No per-tile LDS/barriers.
__global__ __launch_bounds__(256) void k_gather(
    const ushort* __restrict__ g, const int* __restrict__ cnt,
    const int* __restrict__ slots, const int* __restrict__ nf_cnt,
    const float* __restrict__ bias, ushort* __restrict__ pre,
    float* __restrict__ part, int nv, int ntiles) {
  __shared__ float s_red[256][8];

  const int tid = threadIdx.x;
  const int q   = tid & 15;
  const int vg  = tid >> 4;
  const int c8  = q * 8;

  float bs[8];
#pragma unroll
  for (int j = 0; j < 8; ++j) bs[j] = bias[c8 + j];
  float st_s[8], st_q[8];
#pragma unroll
  for (int j = 0; j < 8; ++j) { st_s[j] = 0.f; st_q[j] = 0.f; }

  for (int tile = blockIdx.x; tile < ntiles; tile += gridDim.x) {
    const int v = tile * 16 + vg;
    int deg = cnt[v]; deg = deg > CAP ? CAP : deg;      // lane-broadcast
    const int* sl = &slots[(size_t)v * CAP];

    float a[8];
#pragma unroll
    for (int j = 0; j < 8; ++j) a[j] = 0.f;

    int t = 0;
    for (; t + 4 <= deg; t += 4) {
      const int4 ff = *(const int4*)&sl[t];             // broadcast 16B
      const short8 r0 = *(const short8*)&g[(size_t)ff.x * C_OUT + c8];
      const short8 r1 = *(const short8*)&g[(size_t)ff.y * C_OUT + c8];
      const short8 r2 = *(const short8*)&g[(size_t)ff.z * C_OUT + c8];
      const short8 r3 = *(const short8*)&g[(size_t)ff.w * C_OUT + c8];
#pragma unroll
      for (int j = 0; j < 8; ++j)
        a[j] += (b2f((ushort)r0[j]) + b2f((ushort)r1[j]))
              + (b2f((ushort)r2[j]) + b2f((ushort)r3[j]));
    }
    for (; t < deg; ++t) {
      const short8 r0 = *(const short8*)&g[(size_t)sl[t] * C_OUT + c8];
#pragma unroll
      for (int j = 0; j < 8; ++j) a[j] += b2f((ushort)r0[j]);
    }

    int d = nf_cnt[v]; if (d < 1) d = 1;
    const float inv = 1.0f / (float)d;
    float r[8];
#pragma unroll
    for (int j = 0; j < 8; ++j) {
      r[j] = fmaxf(fmaf(a[j], inv, bs[j]), 0.f);
      st_s[j] += r[j];
      st_q[j] = fmaf(r[j], r[j], st_q[j]);
    }
    uint4 u;
    u.x = pk2(r[0], r[1]); u.y = pk2(r[2], r[3]);
    u.z = pk2(r[4], r[5]); u.w = pk2(r[6], r[7]);
    *(short8*)&pre[(size_t)v * C_OUT + c8] = *(short8*)&u;
  }

  // deterministic block partials: part[col][GB] (transposed)
#pragma unroll
  for (int j = 0; j < 8; ++j) s_red[tid][j] = st_s[j];
  __syncthreads();
  if (tid < 16) {
    for (int j = 0; j < 8; ++j) {
      float x = 0.f;
      for (int gg = 0; gg < 16; ++gg) x += s_red[gg * 16 + tid][j];
      part[(size_t)(tid * 8 + j) * GB + blockIdx.x] = x;
    }
  }
  __syncthreads();
#pragma unroll
  for (int j = 0; j < 8; ++j) s_red[tid][j] = st_q[j];
  __syncthreads();
  if (tid < 16) {
    for (int j = 0; j < 8; ++j) {
      float x = 0.f;
      for (int gg = 0; gg < 16; ++gg) x += s_red[gg * 16 + tid][j];
      part[(size_t)(128 + tid * 8 + j) * GB + blockIdx.x] = x;
    }
  }
}

// 256 blocks: block j reduces part[j][0:GB] (coalesced) -> red[j].
__global__ __launch_bounds__(256) void k_red(const float* __restrict__ part,
                                             float* __restrict__ red) {
  const int j   = blockIdx.x;
  const int tid = threadIdx.x;
  float v = 0.f;
#pragma unroll
  for (int b = 0; b < GB; b += 256) v += part[(size_t)j * GB + b + tid];
#pragma unroll
  for (int off = 32; off > 0; off >>= 1) v += __shfl_down(v, off);
  __shared__ float sred[4];
  if ((tid & 63) == 0) sred[tid >> 6] = v;
  __syncthreads();
  if (tid == 0) red[j] = sred[0] + sred[1] + sred[2] + sred[3];
}

__global__ void k_fin(const float* __restrict__ red,
                      const float* __restrict__ gamma, const float* __restrict__ beta,
                      float* __restrict__ scale, float* __restrict__ shift, float invN) {
  int o = threadIdx.x;   // 128
  float mean = red[o] * invN;
  float var  = red[128 + o] * invN - mean * mean;
  float sc   = gamma[o] * rsqrtf(var + BN_EPS);
  scale[o] = sc;
  shift[o] = fmaf(-mean, sc, beta[o]);
}

// Read bf16 pre (25.6MB), apply affine, write f32 out (51.2MB).
__global__ __launch_bounds__(256) void k_bn(const ushort* __restrict__ pre,
                                            const float* __restrict__ scale,
                                            const float* __restrict__ shift,
                                            float* __restrict__ out, int n8) {
  int idx = blockIdx.x * blockDim.x + threadIdx.x;
  const int stride = gridDim.x * blockDim.x;
  for (; idx < n8; idx += stride) {
    const short8 pv = *(const short8*)&pre[(size_t)idx * 8];
    const int base = (idx * 8) & (C_OUT - 1);
    const float4 sc0 = *(const float4*)&scale[base];
    const float4 sc1 = *(const float4*)&scale[base + 4];
    const float4 sh0 = *(const float4*)&shift[base];
    const float4 sh1 = *(const float4*)&shift[base + 4];
    float4 o0, o1;
    o0.x = fmaf(b2f((ushort)pv[0]), sc0.x, sh0.x);
    o0.y = fmaf(b2f((ushort)pv[1]), sc0.y, sh0.y);
    o0.z = fmaf(b2f((ushort)pv[2]), sc0.z, sh0.z);
    o0.w = fmaf(b2f((ushort)pv[3]), sc0.w, sh0.w);
    o1.x = fmaf(b2f((ushort)pv[4]), sc1.x, sh1.x);
    o1.y = fmaf(b2f((ushort)pv[5]), sc1.y, sh1.y);
    o1.z = fmaf(b2f((ushort)pv[6]), sc1.z, sh1.z);
    o1.w = fmaf(b2f((ushort)pv[7]), sc1.w, sh1.w);
    *(float4*)&out[(size_t)idx * 8]     = o0;
    *(float4*)&out[(size_t)idx * 8 + 4] = o1;
  }
}

extern "C" void kernel_launch(void* const* d_in, const int* in_sizes, int n_in,
                              void* d_out, int out_size, void* d_ws, size_t ws_size,
                              hipStream_t stream) {
  const float* inputs = (const float*)d_in[0];
  const float* fc     = (const float*)d_in[1];
  const int*   face   = (const int*)d_in[2];
  const int*   nf_cnt = (const int*)d_in[3];
  const int*   vt_map = (const int*)d_in[4];
  const float* sw     = (const float*)d_in[5];
  const float* dw     = (const float*)d_in[6];
  const float* bias   = (const float*)d_in[7];
  const float* gamma  = (const float*)d_in[8];
  const float* beta   = (const float*)d_in[9];
  float* out = (float*)d_out;

  const int nf = in_sizes[0] / C_IN;   // 200000
  const int nv = in_sizes[3];          // 100000

  // ws: cnt[nv] | scale[128] | shift[128] | red[256] | part[256*GB]
  //     | dwt[128*256 u16] | swt[256*32 u16] | slots[nv*CAP]
  //     | g[nf*128 u16] | pre[nv*128 u16]
  char* p = (char*)d_ws;
  int*    cnt   = (int*)p;            p += (size_t)nv * 4;
  float*  scale = (float*)p;          p += C_OUT * 4;
  float*  shift = (float*)p;          p += C_OUT * 4;
  float*  red   = (float*)p;          p += 256 * 4;
  float*  part  = (float*)p;          p += (size_t)256 * GB * 4;
  ushort* dwt   = (ushort*)p;         p += (size_t)C_OUT * CM * 2;
  ushort* swt   = (ushort*)p;         p += (size_t)CM * 32 * 2;
  int*    slots = (int*)p;            p += (size_t)nv * CAP * 4;
  ushort* g     = (ushort*)p;         p += (size_t)nf * C_OUT * 2;
  ushort* pre   = (ushort*)p;

  hipMemsetAsync(cnt, 0, (size_t)nv * 4, stream);

  const int n_inc = nf * 3;
  const int fill_blocks = (n_inc + 255) / 256;
  k_prepfill<<<96 + fill_blocks, 256, 0, stream>>>(dw, sw, dwt, swt,
                                                   face, vt_map, cnt, slots, n_inc);

  const int ntiles_f = (nf + FT - 1) / FT;   // 3125
  k_faceg<<<GRIDF, 256, 0, stream>>>(inputs, fc, swt, dwt, g, ntiles_f);

  const int ntiles_v = (nv + 15) / 16;       // 6250
  k_gather<<<GB, 256, 0, stream>>>(g, cnt, slots, nf_cnt, bias, pre, part, nv, ntiles_v);

  k_red<<<256, 256, 0, stream>>>(part, red);
  k_fin<<<1, 128, 0, stream>>>(red, gamma, beta, scale, shift, 1.0f / (float)nv);

  const int n8 = (nv * C_OUT) / 8;           // 1.6M
  k_bn<<<2048, 256, 0, stream>>>(pre, scale, shift, out, n8);
}

// Round 20
// 135.757 us; speedup vs baseline: 1.1448x; 1.1448x over previous
//
#include <hip/hip_runtime.h>
#include <hip/hip_bf16.h>

// F2VConv3d: per-face double-GEMM (both on MFMA) then vertex gather + BN.
//   W[f,:] = fc[f,:] @ sw          (MFMA1, K=16 padded to 32, computed as W^T)
//   feat[f,cm] = inp[f,cm>>1] * W[f,cm]   (epilogue: LDS in-place overwrite)
//   g[f] = feat[f,:] @ dw          (MFMA2)
//   out[v] = BN(relu(mean_{f in N(v)} g[f] + bias))
// R20 (FINAL): revert to the best measured configuration (Round-16 kernel,
// 135.5us). R11-R19 exploration summary: every clean k_faceg variant lands
// 66-69us (latency-structure plateau at 2 blocks/CU); all occupancy/no-DMA
// escapes either spill (WRITE_SIZE jump) or re-expose global-load latency.
// Components: R11 faceg (FT=64, 2x32KB dbuf, counted vmcnt(8), raw barriers,
// source-swizzled global_load_lds DMA), bf16 pre-BN buffer, merged prep+fill,
// transposed-partials BN reduction.

constexpr int C_IN  = 128;
constexpr int KF    = 16;
constexpr int CM    = 256;    // C_IN * MULT
constexpr int C_OUT = 128;
constexpr int CAP   = 32;     // max tracked faces per vertex
constexpr int GB    = 1024;   // k_gather grid (k_red loops over GB)
constexpr int FT    = 64;     // faces per k_faceg tile
constexpr int GRIDF = 512;    // k_faceg grid (2 blocks/CU with 64KB LDS)
constexpr float BN_EPS = 1e-3f;

typedef __attribute__((ext_vector_type(8))) short short8;
typedef __attribute__((ext_vector_type(4))) float f32x4;

__device__ __forceinline__ ushort f2bf(float x) {
  union { float f; unsigned u; } v; v.f = x;
  return (ushort)((v.u + 0x7fffu + ((v.u >> 16) & 1u)) >> 16);
}
__device__ __forceinline__ float b2f(ushort u) {
  return __uint_as_float((unsigned)u << 16);
}
__device__ __forceinline__ uint pk2(float a, float b) {
  __hip_bfloat162 h = __float22bfloat162_rn(float2{a, b});
  return *(uint*)&h;
}
__device__ __forceinline__ void dma16(const float* g, void* l) {
  __builtin_amdgcn_global_load_lds(
      (const __attribute__((address_space(1))) void*)g,
      (__attribute__((address_space(3))) void*)l, 16, 0, 0);
}
__device__ __forceinline__ void bar_raw() {
  __builtin_amdgcn_s_barrier();
  asm volatile("" ::: "memory");
}
__device__ __forceinline__ void bar_lds() {
  asm volatile("s_waitcnt lgkmcnt(0)" ::: "memory");
  __builtin_amdgcn_s_barrier();
  asm volatile("" ::: "memory");
}

// Merged prep + fill. Blocks 0..95: dwt/swt transform. Blocks 96..: CSR fill.
__global__ __launch_bounds__(256) void k_prepfill(
    const float* __restrict__ dw, const float* __restrict__ sw,
    ushort* __restrict__ dwt, ushort* __restrict__ swt,
    const int* __restrict__ face, const int* __restrict__ vt_map,
    int* __restrict__ cnt, int* __restrict__ slots, int n_inc) {
  const int b = blockIdx.x, tid = threadIdx.x;
  if (b < 64) {                       // dwt: 128*256 elems, 2/thread
    int i = b * 512 + tid;
#pragma unroll
    for (int r = 0; r < 2; ++r, i += 256) {
      int n = i >> 8, k = i & 255;
      dwt[i] = f2bf(dw[k * C_OUT + n]);
    }
  } else if (b < 96) {                // swt: 256*32 elems, 1/thread
    int i = (b - 64) * 256 + tid;
    int cm = i >> 5, k = i & 31;
    swt[i] = (k < KF) ? f2bf(sw[k * CM + cm]) : (ushort)0;
  } else {                            // fill
    int i = (b - 96) * 256 + tid;
    if (i < n_inc) {
      int f = i / 3;
      int v = vt_map[face[i]];
      int p = atomicAdd(&cnt[v], 1);
      if (p < CAP) slots[(size_t)v * CAP + p] = f;
    }
  }
}

// Persistent pipelined k_faceg: FT=64, 2x32KB dbuf, 2 blocks/CU, counted
// vmcnt(8), raw barriers. Per tile: [TOP bar_lds] [fc loads, prefetch-DMA
// next] [vmcnt(8)] [b1 build] [bar A] [MFMA1+epi in-place] [bar B] [MFMA2]
// [bar C] [f32 staging] [bar D] [g stores].
__global__ __launch_bounds__(256, 2) void k_faceg(
    const float* __restrict__ inp, const float* __restrict__ fc,
    const ushort* __restrict__ swt, const ushort* __restrict__ dwt,
    ushort* __restrict__ g, int ntiles) {
  __shared__ __align__(1024) ushort s_buf[2][FT * 256];   // 2 x 32768 B

  const int tid  = threadIdx.x;
  const int w    = tid >> 6;        // wave -> cm range [w*64, w*64+64)
  const int lane = tid & 63;
  const int rm   = lane & 15;
  const int kg   = lane >> 4;

  // loop-invariant fragments (budget: launch_bounds(256,2) -> 256 VGPR)
  short8 a1[4];
#pragma unroll
  for (int ct = 0; ct < 4; ++ct)
    a1[ct] = *(const short8*)&swt[(size_t)(w * 64 + ct * 16 + rm) * 32 + kg * 8];
  short8 bfr[2][8];
#pragma unroll
  for (int nt = 0; nt < 2; ++nt) {
    const int n = (w * 2 + nt) * 16 + rm;
#pragma unroll
    for (int ks = 0; ks < 8; ++ks)
      bfr[nt][ks] = *(const short8*)&dwt[n * 256 + ks * 32 + kg * 8];
  }

  auto issue_dma = [&](int buf, int fb) {
#pragma unroll
    for (int it = 0; it < 8; ++it) {
      const int row   = w * 16 + it * 2 + (lane >> 5);
      const int chunk = lane & 31;
      const float* src = inp + (size_t)(fb + row) * C_IN + ((chunk ^ (row & 7)) << 2);
      dma16(src, (char*)s_buf + buf * 32768 + w * 8192 + it * 1024);
    }
  };

  int t = blockIdx.x;
  issue_dma(0, t * FT);
  int cur = 0;

  for (; t < ntiles; t += GRIDF, cur ^= 1) {
    const int fb = t * FT;
    char* sb = (char*)s_buf + cur * 32768;

    bar_lds();                        // TOP: prev iter's LDS reads drained

    float4 p0[4], p1[4];
#pragma unroll
    for (int ft = 0; ft < 4; ++ft) {
      const float* fr = &fc[(size_t)(fb + ft * 16 + rm) * KF + (kg & 1) * 8];
      p0[ft] = *(const float4*)fr;
      p1[ft] = *(const float4*)(fr + 4);
    }

    const int tn = t + GRIDF;
    if (tn < ntiles) {
      issue_dma(cur ^ 1, tn * FT);
      asm volatile("s_waitcnt vmcnt(8)" ::: "memory");
    } else {
      asm volatile("s_waitcnt vmcnt(0)" ::: "memory");
    }

    short8 b1[4];
#pragma unroll
    for (int ft = 0; ft < 4; ++ft) {
      uint4 u;
      u.x = pk2(p0[ft].x, p0[ft].y); u.y = pk2(p0[ft].z, p0[ft].w);
      u.z = pk2(p1[ft].x, p1[ft].y); u.w = pk2(p1[ft].z, p1[ft].w);
      if (kg >= 2) u = uint4{0, 0, 0, 0};
      b1[ft] = *(short8*)&u;
    }

    bar_raw();                        // A: buf[cur] fully DMA'd

    // MFMA1 + epilogue: feat bf16 overwrites inp f32 in place
#pragma unroll
    for (int ft = 0; ft < 4; ++ft) {
#pragma unroll
      for (int ct = 0; ct < 4; ++ct) {
        f32x4 acc = {0.f, 0.f, 0.f, 0.f};
        acc = __builtin_amdgcn_mfma_f32_16x16x32_bf16(a1[ct], b1[ft], acc, 0, 0, 0);
        const int face = ft * 16 + rm;
        const int cmb  = w * 64 + ct * 16 + kg * 4;
        const int byt  = face * 512 + ((((cmb * 2) >> 4) ^ (face & 7)) << 4)
                       + ((cmb * 2) & 15);
        const float2 ivv = *(const float2*)(sb + byt);
        uint2 pw;
        pw.x = pk2(acc[0] * ivv.x, acc[1] * ivv.x);
        pw.y = pk2(acc[2] * ivv.y, acc[3] * ivv.y);
        *(uint2*)(sb + byt) = pw;
      }
    }

    bar_lds();                        // B: feat ready

    f32x4 acc2[4][2];
#pragma unroll
    for (int fs = 0; fs < 4; ++fs)
#pragma unroll
      for (int nt = 0; nt < 2; ++nt)
        acc2[fs][nt] = (f32x4){0.f, 0.f, 0.f, 0.f};

#pragma unroll
    for (int fs = 0; fs < 4; ++fs)
#pragma unroll
      for (int ks = 0; ks < 8; ++ks) {
        const int row = fs * 16 + rm;
        const int byt = row * 512 + (((ks * 4 + kg) ^ (row & 7)) << 4);
        const short8 af = *(const short8*)(sb + byt);
        acc2[fs][0] = __builtin_amdgcn_mfma_f32_16x16x32_bf16(af, bfr[0][ks], acc2[fs][0], 0, 0, 0);
        acc2[fs][1] = __builtin_amdgcn_mfma_f32_16x16x32_bf16(af, bfr[1][ks], acc2[fs][1], 0, 0, 0);
      }

    bar_lds();                        // C: all feat reads done (alias!)

#pragma unroll
    for (int fs = 0; fs < 4; ++fs)
#pragma unroll
      for (int nt = 0; nt < 2; ++nt)
#pragma unroll
        for (int r = 0; r < 4; ++r) {
          const int row = fs * 16 + kg * 4 + r;
          const int col = (w * 2 + nt) * 16 + rm;
          const int byt = row * 512 + (((col >> 2) ^ (row & 7)) << 4) + (col & 3) * 4;
          *(float*)(sb + byt) = acc2[fs][nt][r];
        }

    bar_lds();                        // D: staging ready

    // packed bf16 g stores: thread (row=tid>>2, q=tid&3), chunk pairs 2q+8i
    const int irow = tid >> 2;
    const int q    = tid & 3;
#pragma unroll
    for (int i = 0; i < 4; ++i) {
      const int c0 = 2 * q + 8 * i;
      const float4 a = *(const float4*)(sb + irow * 512 + ((c0 ^ (irow & 7)) << 4));
      const float4 b = *(const float4*)(sb + irow * 512 + (((c0 + 1) ^ (irow & 7)) << 4));
      uint4 u;
      u.x = pk2(a.x, a.y); u.y = pk2(a.z, a.w);
      u.z = pk2(b.x, b.y); u.w = pk2(b.z, b.w);
      *(short8*)&g[(size_t)(fb + irow) * C_OUT + c0 * 4] = *(short8*)&u;
    }
  }
}

// 16 verts/tile, 16 threads/vert. Writes bf16 pre-BN buffer (half traffic);
// partials transposed part[col][GB]. No per-tile LDS/barriers.
__global__ __launch_bounds__(256) void k_gather(
    const ushort* __restrict__ g, const int* __restrict__ cnt,
    const int* __restrict__ slots, const int* __restrict__ nf_cnt,
    const float* __restrict__ bias, ushort* __restrict__ pre,
    float* __restrict__ part, int nv, int ntiles) {
  __shared__ float s_red[256][8];

  const int tid = threadIdx.x;
  const int q   = tid & 15;
  const int vg  = tid >> 4;
  const int c8  = q * 8;

  float bs[8];
#pragma unroll
  for (int j = 0; j < 8; ++j) bs[j] = bias[c8 + j];
  float st_s[8], st_q[8];
#pragma unroll
  for (int j = 0; j < 8; ++j) { st_s[j] = 0.f; st_q[j] = 0.f; }

  for (int tile = blockIdx.x; tile < ntiles; tile += gridDim.x) {
    const int v = tile * 16 + vg;
    int deg = cnt[v]; deg = deg > CAP ? CAP : deg;      // lane-broadcast
    const int* sl = &slots[(size_t)v * CAP];

    float a[8];
#pragma unroll
    for (int j = 0; j < 8; ++j) a[j] = 0.f;

    int t = 0;
    for (; t + 4 <= deg; t += 4) {
      const int4 ff = *(const int4*)&sl[t];             // broadcast 16B
      const short8 r0 = *(const short8*)&g[(size_t)ff.x * C_OUT + c8];
      const short8 r1 = *(const short8*)&g[(size_t)ff.y * C_OUT + c8];
      const short8 r2 = *(const short8*)&g[(size_t)ff.z * C_OUT + c8];
      const short8 r3 = *(const short8*)&g[(size_t)ff.w * C_OUT + c8];
#pragma unroll
      for (int j = 0; j < 8; ++j)
        a[j] += (b2f((ushort)r0[j]) + b2f((ushort)r1[j]))
              + (b2f((ushort)r2[j]) + b2f((ushort)r3[j]));
    }
    for (; t < deg; ++t) {
      const short8 r0 = *(const short8*)&g[(size_t)sl[t] * C_OUT + c8];
#pragma unroll
      for (int j = 0; j < 8; ++j) a[j] += b2f((ushort)r0[j]);
    }

    int d = nf_cnt[v]; if (d < 1) d = 1;
    const float inv = 1.0f / (float)d;
    float r[8];
#pragma unroll
    for (int j = 0; j < 8; ++j) {
      r[j] = fmaxf(fmaf(a[j], inv, bs[j]), 0.f);
      st_s[j] += r[j];
      st_q[j] = fmaf(r[j], r[j], st_q[j]);
    }
    uint4 u;
    u.x = pk2(r[0], r[1]); u.y = pk2(r[2], r[3]);
    u.z = pk2(r[4], r[5]); u.w = pk2(r[6], r[7]);
    *(short8*)&pre[(size_t)v * C_OUT + c8] = *(short8*)&u;
  }

  // deterministic block partials: part[col][GB] (transposed)
#pragma unroll
  for (int j = 0; j < 8; ++j) s_red[tid][j] = st_s[j];
  __syncthreads();
  if (tid < 16) {
    for (int j = 0; j < 8; ++j) {
      float x = 0.f;
      for (int gg = 0; gg < 16; ++gg) x += s_red[gg * 16 + tid][j];
      part[(size_t)(tid * 8 + j) * GB + blockIdx.x] = x;
    }
  }
  __syncthreads();
#pragma unroll
  for (int j = 0; j < 8; ++j) s_red[tid][j] = st_q[j];
  __syncthreads();
  if (tid < 16) {
    for (int j = 0; j < 8; ++j) {
      float x = 0.f;
      for (int gg = 0; gg < 16; ++gg) x += s_red[gg * 16 + tid][j];
      part[(size_t)(128 + tid * 8 + j) * GB + blockIdx.x] = x;
    }
  }
}

// 256 blocks: block j reduces part[j][0:GB] (coalesced) -> red[j].
__global__ __launch_bounds__(256) void k_red(const float* __restrict__ part,
                                             float* __restrict__ red) {
  const int j   = blockIdx.x;
  const int tid = threadIdx.x;
  float v = 0.f;
#pragma unroll
  for (int b = 0; b < GB; b += 256) v += part[(size_t)j * GB + b + tid];
#pragma unroll
  for (int off = 32; off > 0; off >>= 1) v += __shfl_down(v, off);
  __shared__ float sred[4];
  if ((tid & 63) == 0) sred[tid >> 6] = v;
  __syncthreads();
  if (tid == 0) red[j] = sred[0] + sred[1] + sred[2] + sred[3];
}

__global__ void k_fin(const float* __restrict__ red,
                      const float* __restrict__ gamma, const float* __restrict__ beta,
                      float* __restrict__ scale, float* __restrict__ shift, float invN) {
  int o = threadIdx.x;   // 128
  float mean = red[o] * invN;
  float var  = red[128 + o] * invN - mean * mean;
  float sc   = gamma[o] * rsqrtf(var + BN_EPS);
  scale[o] = sc;
  shift[o] = fmaf(-mean, sc, beta[o]);
}

// Read bf16 pre (25.6MB), apply affine, write f32 out (51.2MB).
__global__ __launch_bounds__(256) void k_bn(const ushort* __restrict__ pre,
                                            const float* __restrict__ scale,
                                            const float* __restrict__ shift,
                                            float* __restrict__ out, int n8) {
  int idx = blockIdx.x * blockDim.x + threadIdx.x;
  const int stride = gridDim.x * blockDim.x;
  for (; idx < n8; idx += stride) {
    const short8 pv = *(const short8*)&pre[(size_t)idx * 8];
    const int base = (idx * 8) & (C_OUT - 1);
    const float4 sc0 = *(const float4*)&scale[base];
    const float4 sc1 = *(const float4*)&scale[base + 4];
    const float4 sh0 = *(const float4*)&shift[base];
    const float4 sh1 = *(const float4*)&shift[base + 4];
    float4 o0, o1;
    o0.x = fmaf(b2f((ushort)pv[0]), sc0.x, sh0.x);
    o0.y = fmaf(b2f((ushort)pv[1]), sc0.y, sh0.y);
    o0.z = fmaf(b2f((ushort)pv[2]), sc0.z, sh0.z);
    o0.w = fmaf(b2f((ushort)pv[3]), sc0.w, sh0.w);
    o1.x = fmaf(b2f((ushort)pv[4]), sc1.x, sh1.x);
    o1.y = fmaf(b2f((ushort)pv[5]), sc1.y, sh1.y);
    o1.z = fmaf(b2f((ushort)pv[6]), sc1.z, sh1.z);
    o1.w = fmaf(b2f((ushort)pv[7]), sc1.w, sh1.w);
    *(float4*)&out[(size_t)idx * 8]     = o0;
    *(float4*)&out[(size_t)idx * 8 + 4] = o1;
  }
}

extern "C" void kernel_launch(void* const* d_in, const int* in_sizes, int n_in,
                              void* d_out, int out_size, void* d_ws, size_t ws_size,
                              hipStream_t stream) {
  const float* inputs = (const float*)d_in[0];
  const float* fc     = (const float*)d_in[1];
  const int*   face   = (const int*)d_in[2];
  const int*   nf_cnt = (const int*)d_in[3];
  const int*   vt_map = (const int*)d_in[4];
  const float* sw     = (const float*)d_in[5];
  const float* dw     = (const float*)d_in[6];
  const float* bias   = (const float*)d_in[7];
  const float* gamma  = (const float*)d_in[8];
  const float* beta   = (const float*)d_in[9];
  float* out = (float*)d_out;

  const int nf = in_sizes[0] / C_IN;   // 200000
  const int nv = in_sizes[3];          // 100000

  // ws: cnt[nv] | scale[128] | shift[128] | red[256] | part[256*GB]
  //     | dwt[128*256 u16] | swt[256*32 u16] | slots[nv*CAP]
  //     | g[nf*128 u16] | pre[nv*128 u16]
  char* p = (char*)d_ws;
  int*    cnt   = (int*)p;            p += (size_t)nv * 4;
  float*  scale = (float*)p;          p += C_OUT * 4;
  float*  shift = (float*)p;          p += C_OUT * 4;
  float*  red   = (float*)p;          p += 256 * 4;
  float*  part  = (float*)p;          p += (size_t)256 * GB * 4;
  ushort* dwt   = (ushort*)p;         p += (size_t)C_OUT * CM * 2;
  ushort* swt   = (ushort*)p;         p += (size_t)CM * 32 * 2;
  int*    slots = (int*)p;            p += (size_t)nv * CAP * 4;
  ushort* g     = (ushort*)p;         p += (size_t)nf * C_OUT * 2;
  ushort* pre   = (ushort*)p;

  hipMemsetAsync(cnt, 0, (size_t)nv * 4, stream);

  const int n_inc = nf * 3;
  const int fill_blocks = (n_inc + 255) / 256;
  k_prepfill<<<96 + fill_blocks, 256, 0, stream>>>(dw, sw, dwt, swt,
                                                   face, vt_map, cnt, slots, n_inc);

  const int ntiles_f = (nf + FT - 1) / FT;   // 3125
  k_faceg<<<GRIDF, 256, 0, stream>>>(inputs, fc, swt, dwt, g, ntiles_f);

  const int ntiles_v = (nv + 15) / 16;       // 6250
  k_gather<<<GB, 256, 0, stream>>>(g, cnt, slots, nf_cnt, bias, pre, part, nv, ntiles_v);

  k_red<<<256, 256, 0, stream>>>(part, red);
  k_fin<<<1, 128, 0, stream>>>(red, gamma, beta, scale, shift, 1.0f / (float)nv);

  const int n8 = (nv * C_OUT) / 8;           // 1.6M
  k_bn<<<2048, 256, 0, stream>>>(pre, scale, shift, out, n8);
}

// Round 21
// 133.452 us; speedup vs baseline: 1.1646x; 1.0173x over previous
//
#include <hip/hip_runtime.h>
#include <hip/hip_bf16.h>

// F2VConv3d: per-face double-GEMM (both on MFMA) then vertex gather + BN.
//   W[f,:] = fc[f,:] @ sw          (MFMA1, K=16 padded to 32, computed as W^T)
//   feat[f,cm] = inp[f,cm>>1] * W[f,cm]   (epilogue: LDS in-place overwrite)
//   g[f] = feat[f,:] @ dw          (MFMA2)
//   out[v] = BN(relu(mean_{f in N(v)} g[f] + bias))
// R21: R20 (best, 135.7us) + k_red/k_fin merged into k_redfin (128 blocks,
// block o reduces sum+sumsq for channel o and writes scale/shift directly)
// -> one fewer launch, no serial 1-block kernel.
// faceg plateau note: 9 structural variants all land 66-69us when counters
// are clean (R11-R19); the documented path past this is inline-asm K-loop /
// wave specialization, not parameter tuning.

constexpr int C_IN  = 128;
constexpr int KF    = 16;
constexpr int CM    = 256;    // C_IN * MULT
constexpr int C_OUT = 128;
constexpr int CAP   = 32;     // max tracked faces per vertex
constexpr int GB    = 1024;   // k_gather grid (k_redfin loops over GB)
constexpr int FT    = 64;     // faces per k_faceg tile
constexpr int GRIDF = 512;    // k_faceg grid (2 blocks/CU with 64KB LDS)
constexpr float BN_EPS = 1e-3f;

typedef __attribute__((ext_vector_type(8))) short short8;
typedef __attribute__((ext_vector_type(4))) float f32x4;

__device__ __forceinline__ ushort f2bf(float x) {
  union { float f; unsigned u; } v; v.f = x;
  return (ushort)((v.u + 0x7fffu + ((v.u >> 16) & 1u)) >> 16);
}
__device__ __forceinline__ float b2f(ushort u) {
  return __uint_as_float((unsigned)u << 16);
}
__device__ __forceinline__ uint pk2(float a, float b) {
  __hip_bfloat162 h = __float22bfloat162_rn(float2{a, b});
  return *(uint*)&h;
}
__device__ __forceinline__ void dma16(const float* g, void* l) {
  __builtin_amdgcn_global_load_lds(
      (const __attribute__((address_space(1))) void*)g,
      (__attribute__((address_space(3))) void*)l, 16, 0, 0);
}
__device__ __forceinline__ void bar_raw() {
  __builtin_amdgcn_s_barrier();
  asm volatile("" ::: "memory");
}
__device__ __forceinline__ void bar_lds() {
  asm volatile("s_waitcnt lgkmcnt(0)" ::: "memory");
  __builtin_amdgcn_s_barrier();
  asm volatile("" ::: "memory");
}

// Merged prep + fill. Blocks 0..95: dwt/swt transform. Blocks 96..: CSR fill.
__global__ __launch_bounds__(256) void k_prepfill(
    const float* __restrict__ dw, const float* __restrict__ sw,
    ushort* __restrict__ dwt, ushort* __restrict__ swt,
    const int* __restrict__ face, const int* __restrict__ vt_map,
    int* __restrict__ cnt, int* __restrict__ slots, int n_inc) {
  const int b = blockIdx.x, tid = threadIdx.x;
  if (b < 64) {                       // dwt: 128*256 elems, 2/thread
    int i = b * 512 + tid;
#pragma unroll
    for (int r = 0; r < 2; ++r, i += 256) {
      int n = i >> 8, k = i & 255;
      dwt[i] = f2bf(dw[k * C_OUT + n]);
    }
  } else if (b < 96) {                // swt: 256*32 elems, 1/thread
    int i = (b - 64) * 256 + tid;
    int cm = i >> 5, k = i & 31;
    swt[i] = (k < KF) ? f2bf(sw[k * CM + cm]) : (ushort)0;
  } else {                            // fill
    int i = (b - 96) * 256 + tid;
    if (i < n_inc) {
      int f = i / 3;
      int v = vt_map[face[i]];
      int p = atomicAdd(&cnt[v], 1);
      if (p < CAP) slots[(size_t)v * CAP + p] = f;
    }
  }
}

// Persistent pipelined k_faceg: FT=64, 2x32KB dbuf, 2 blocks/CU, counted
// vmcnt(8), raw barriers. Per tile: [TOP bar_lds] [fc loads, prefetch-DMA
// next] [vmcnt(8)] [b1 build] [bar A] [MFMA1+epi in-place] [bar B] [MFMA2]
// [bar C] [f32 staging] [bar D] [g stores].
__global__ __launch_bounds__(256, 2) void k_faceg(
    const float* __restrict__ inp, const float* __restrict__ fc,
    const ushort* __restrict__ swt, const ushort* __restrict__ dwt,
    ushort* __restrict__ g, int ntiles) {
  __shared__ __align__(1024) ushort s_buf[2][FT * 256];   // 2 x 32768 B

  const int tid  = threadIdx.x;
  const int w    = tid >> 6;        // wave -> cm range [w*64, w*64+64)
  const int lane = tid & 63;
  const int rm   = lane & 15;
  const int kg   = lane >> 4;

  // loop-invariant fragments (budget: launch_bounds(256,2) -> 256 VGPR)
  short8 a1[4];
#pragma unroll
  for (int ct = 0; ct < 4; ++ct)
    a1[ct] = *(const short8*)&swt[(size_t)(w * 64 + ct * 16 + rm) * 32 + kg * 8];
  short8 bfr[2][8];
#pragma unroll
  for (int nt = 0; nt < 2; ++nt) {
    const int n = (w * 2 + nt) * 16 + rm;
#pragma unroll
    for (int ks = 0; ks < 8; ++ks)
      bfr[nt][ks] = *(const short8*)&dwt[n * 256 + ks * 32 + kg * 8];
  }

  auto issue_dma = [&](int buf, int fb) {
#pragma unroll
    for (int it = 0; it < 8; ++it) {
      const int row   = w * 16 + it * 2 + (lane >> 5);
      const int chunk = lane & 31;
      const float* src = inp + (size_t)(fb + row) * C_IN + ((chunk ^ (row & 7)) << 2);
      dma16(src, (char*)s_buf + buf * 32768 + w * 8192 + it * 1024);
    }
  };

  int t = blockIdx.x;
  issue_dma(0, t * FT);
  int cur = 0;

  for (; t < ntiles; t += GRIDF, cur ^= 1) {
    const int fb = t * FT;
    char* sb = (char*)s_buf + cur * 32768;

    bar_lds();                        // TOP: prev iter's LDS reads drained

    float4 p0[4], p1[4];
#pragma unroll
    for (int ft = 0; ft < 4; ++ft) {
      const float* fr = &fc[(size_t)(fb + ft * 16 + rm) * KF + (kg & 1) * 8];
      p0[ft] = *(const float4*)fr;
      p1[ft] = *(const float4*)(fr + 4);
    }

    const int tn = t + GRIDF;
    if (tn < ntiles) {
      issue_dma(cur ^ 1, tn * FT);
      asm volatile("s_waitcnt vmcnt(8)" ::: "memory");
    } else {
      asm volatile("s_waitcnt vmcnt(0)" ::: "memory");
    }

    short8 b1[4];
#pragma unroll
    for (int ft = 0; ft < 4; ++ft) {
      uint4 u;
      u.x = pk2(p0[ft].x, p0[ft].y); u.y = pk2(p0[ft].z, p0[ft].w);
      u.z = pk2(p1[ft].x, p1[ft].y); u.w = pk2(p1[ft].z, p1[ft].w);
      if (kg >= 2) u = uint4{0, 0, 0, 0};
      b1[ft] = *(short8*)&u;
    }

    bar_raw();                        // A: buf[cur] fully DMA'd

    // MFMA1 + epilogue: feat bf16 overwrites inp f32 in place
#pragma unroll
    for (int ft = 0; ft < 4; ++ft) {
#pragma unroll
      for (int ct = 0; ct < 4; ++ct) {
        f32x4 acc = {0.f, 0.f, 0.f, 0.f};
        acc = __builtin_amdgcn_mfma_f32_16x16x32_bf16(a1[ct], b1[ft], acc, 0, 0, 0);
        const int face = ft * 16 + rm;
        const int cmb  = w * 64 + ct * 16 + kg * 4;
        const int byt  = face * 512 + ((((cmb * 2) >> 4) ^ (face & 7)) << 4)
                       + ((cmb * 2) & 15);
        const float2 ivv = *(const float2*)(sb + byt);
        uint2 pw;
        pw.x = pk2(acc[0] * ivv.x, acc[1] * ivv.x);
        pw.y = pk2(acc[2] * ivv.y, acc[3] * ivv.y);
        *(uint2*)(sb + byt) = pw;
      }
    }

    bar_lds();                        // B: feat ready

    f32x4 acc2[4][2];
#pragma unroll
    for (int fs = 0; fs < 4; ++fs)
#pragma unroll
      for (int nt = 0; nt < 2; ++nt)
        acc2[fs][nt] = (f32x4){0.f, 0.f, 0.f, 0.f};

#pragma unroll
    for (int fs = 0; fs < 4; ++fs)
#pragma unroll
      for (int ks = 0; ks < 8; ++ks) {
        const int row = fs * 16 + rm;
        const int byt = row * 512 + (((ks * 4 + kg) ^ (row & 7)) << 4);
        const short8 af = *(const short8*)(sb + byt);
        acc2[fs][0] = __builtin_amdgcn_mfma_f32_16x16x32_bf16(af, bfr[0][ks], acc2[fs][0], 0, 0, 0);
        acc2[fs][1] = __builtin_amdgcn_mfma_f32_16x16x32_bf16(af, bfr[1][ks], acc2[fs][1], 0, 0, 0);
      }

    bar_lds();                        // C: all feat reads done (alias!)

#pragma unroll
    for (int fs = 0; fs < 4; ++fs)
#pragma unroll
      for (int nt = 0; nt < 2; ++nt)
#pragma unroll
        for (int r = 0; r < 4; ++r) {
          const int row = fs * 16 + kg * 4 + r;
          const int col = (w * 2 + nt) * 16 + rm;
          const int byt = row * 512 + (((col >> 2) ^ (row & 7)) << 4) + (col & 3) * 4;
          *(float*)(sb + byt) = acc2[fs][nt][r];
        }

    bar_lds();                        // D: staging ready

    // packed bf16 g stores: thread (row=tid>>2, q=tid&3), chunk pairs 2q+8i
    const int irow = tid >> 2;
    const int q    = tid & 3;
#pragma unroll
    for (int i = 0; i < 4; ++i) {
      const int c0 = 2 * q + 8 * i;
      const float4 a = *(const float4*)(sb + irow * 512 + ((c0 ^ (irow & 7)) << 4));
      const float4 b = *(const float4*)(sb + irow * 512 + (((c0 + 1) ^ (irow & 7)) << 4));
      uint4 u;
      u.x = pk2(a.x, a.y); u.y = pk2(a.z, a.w);
      u.z = pk2(b.x, b.y); u.w = pk2(b.z, b.w);
      *(short8*)&g[(size_t)(fb + irow) * C_OUT + c0 * 4] = *(short8*)&u;
    }
  }
}

// 16 verts/tile, 16 threads/vert. Writes bf16 pre-BN buffer (half traffic);
// partials transposed part[col][GB]. No per-tile LDS/barriers.
__global__ __launch_bounds__(256) void k_gather(
    const ushort* __restrict__ g, const int* __restrict__ cnt,
    const int* __restrict__ slots, const int* __restrict__ nf_cnt,
    const float* __restrict__ bias, ushort* __restrict__ pre,
    float* __restrict__ part, int nv, int ntiles) {
  __shared__ float s_red[256][8];

  const int tid = threadIdx.x;
  const int q   = tid & 15;
  const int vg  = tid >> 4;
  const int c8  = q * 8;

  float bs[8];
#pragma unroll
  for (int j = 0; j < 8; ++j) bs[j] = bias[c8 + j];
  float st_s[8], st_q[8];
#pragma unroll
  for (int j = 0; j < 8; ++j) { st_s[j] = 0.f; st_q[j] = 0.f; }

  for (int tile = blockIdx.x; tile < ntiles; tile += gridDim.x) {
    const int v = tile * 16 + vg;
    int deg = cnt[v]; deg = deg > CAP ? CAP : deg;      // lane-broadcast
    const int* sl = &slots[(size_t)v * CAP];

    float a[8];
#pragma unroll
    for (int j = 0; j < 8; ++j) a[j] = 0.f;

    int t = 0;
    for (; t + 4 <= deg; t += 4) {
      const int4 ff = *(const int4*)&sl[t];             // broadcast 16B
      const short8 r0 = *(const short8*)&g[(size_t)ff.x * C_OUT + c8];
      const short8 r1 = *(const short8*)&g[(size_t)ff.y * C_OUT + c8];
      const short8 r2 = *(const short8*)&g[(size_t)ff.z * C_OUT + c8];
      const short8 r3 = *(const short8*)&g[(size_t)ff.w * C_OUT + c8];
#pragma unroll
      for (int j = 0; j < 8; ++j)
        a[j] += (b2f((ushort)r0[j]) + b2f((ushort)r1[j]))
              + (b2f((ushort)r2[j]) + b2f((ushort)r3[j]));
    }
    for (; t < deg; ++t) {
      const short8 r0 = *(const short8*)&g[(size_t)sl[t] * C_OUT + c8];
#pragma unroll
      for (int j = 0; j < 8; ++j) a[j] += b2f((ushort)r0[j]);
    }

    int d = nf_cnt[v]; if (d < 1) d = 1;
    const float inv = 1.0f / (float)d;
    float r[8];
#pragma unroll
    for (int j = 0; j < 8; ++j) {
      r[j] = fmaxf(fmaf(a[j], inv, bs[j]), 0.f);
      st_s[j] += r[j];
      st_q[j] = fmaf(r[j], r[j], st_q[j]);
    }
    uint4 u;
    u.x = pk2(r[0], r[1]); u.y = pk2(r[2], r[3]);
    u.z = pk2(r[4], r[5]); u.w = pk2(r[6], r[7]);
    *(short8*)&pre[(size_t)v * C_OUT + c8] = *(short8*)&u;
  }

  // deterministic block partials: part[col][GB] (transposed)
#pragma unroll
  for (int j = 0; j < 8; ++j) s_red[tid][j] = st_s[j];
  __syncthreads();
  if (tid < 16) {
    for (int j = 0; j < 8; ++j) {
      float x = 0.f;
      for (int gg = 0; gg < 16; ++gg) x += s_red[gg * 16 + tid][j];
      part[(size_t)(tid * 8 + j) * GB + blockIdx.x] = x;
    }
  }
  __syncthreads();
#pragma unroll
  for (int j = 0; j < 8; ++j) s_red[tid][j] = st_q[j];
  __syncthreads();
  if (tid < 16) {
    for (int j = 0; j < 8; ++j) {
      float x = 0.f;
      for (int gg = 0; gg < 16; ++gg) x += s_red[gg * 16 + tid][j];
      part[(size_t)(128 + tid * 8 + j) * GB + blockIdx.x] = x;
    }
  }
}

// 128 blocks: block o reduces part[o][0:GB] (sum) and part[128+o][0:GB]
// (sumsq), both coalesced, then writes scale[o]/shift[o] directly.
__global__ __launch_bounds__(256) void k_redfin(
    const float* __restrict__ part, const float* __restrict__ gamma,
    const float* __restrict__ beta, float* __restrict__ scale,
    float* __restrict__ shift, float invN) {
  const int o   = blockIdx.x;        // channel 0..127
  const int tid = threadIdx.x;
  float vs = 0.f, vq = 0.f;
#pragma unroll
  for (int b = 0; b < GB; b += 256) {
    vs += part[(size_t)o * GB + b + tid];
    vq += part[(size_t)(128 + o) * GB + b + tid];
  }
#pragma unroll
  for (int off = 32; off > 0; off >>= 1) {
    vs += __shfl_down(vs, off);
    vq += __shfl_down(vq, off);
  }
  __shared__ float sred[8];
  if ((tid & 63) == 0) {
    sred[tid >> 6]     = vs;
    sred[4 + (tid >> 6)] = vq;
  }
  __syncthreads();
  if (tid == 0) {
    const float s  = sred[0] + sred[1] + sred[2] + sred[3];
    const float sq = sred[4] + sred[5] + sred[6] + sred[7];
    const float mean = s * invN;
    const float var  = sq * invN - mean * mean;
    const float sc   = gamma[o] * rsqrtf(var + BN_EPS);
    scale[o] = sc;
    shift[o] = fmaf(-mean, sc, beta[o]);
  }
}

// Read bf16 pre (25.6MB), apply affine, write f32 out (51.2MB).
__global__ __launch_bounds__(256) void k_bn(const ushort* __restrict__ pre,
                                            const float* __restrict__ scale,
                                            const float* __restrict__ shift,
                                            float* __restrict__ out, int n8) {
  int idx = blockIdx.x * blockDim.x + threadIdx.x;
  const int stride = gridDim.x * blockDim.x;
  for (; idx < n8; idx += stride) {
    const short8 pv = *(const short8*)&pre[(size_t)idx * 8];
    const int base = (idx * 8) & (C_OUT - 1);
    const float4 sc0 = *(const float4*)&scale[base];
    const float4 sc1 = *(const float4*)&scale[base + 4];
    const float4 sh0 = *(const float4*)&shift[base];
    const float4 sh1 = *(const float4*)&shift[base + 4];
    float4 o0, o1;
    o0.x = fmaf(b2f((ushort)pv[0]), sc0.x, sh0.x);
    o0.y = fmaf(b2f((ushort)pv[1]), sc0.y, sh0.y);
    o0.z = fmaf(b2f((ushort)pv[2]), sc0.z, sh0.z);
    o0.w = fmaf(b2f((ushort)pv[3]), sc0.w, sh0.w);
    o1.x = fmaf(b2f((ushort)pv[4]), sc1.x, sh1.x);
    o1.y = fmaf(b2f((ushort)pv[5]), sc1.y, sh1.y);
    o1.z = fmaf(b2f((ushort)pv[6]), sc1.z, sh1.z);
    o1.w = fmaf(b2f((ushort)pv[7]), sc1.w, sh1.w);
    *(float4*)&out[(size_t)idx * 8]     = o0;
    *(float4*)&out[(size_t)idx * 8 + 4] = o1;
  }
}

extern "C" void kernel_launch(void* const* d_in, const int* in_sizes, int n_in,
                              void* d_out, int out_size, void* d_ws, size_t ws_size,
                              hipStream_t stream) {
  const float* inputs = (const float*)d_in[0];
  const float* fc     = (const float*)d_in[1];
  const int*   face   = (const int*)d_in[2];
  const int*   nf_cnt = (const int*)d_in[3];
  const int*   vt_map = (const int*)d_in[4];
  const float* sw     = (const float*)d_in[5];
  const float* dw     = (const float*)d_in[6];
  const float* bias   = (const float*)d_in[7];
  const float* gamma  = (const float*)d_in[8];
  const float* beta   = (const float*)d_in[9];
  float* out = (float*)d_out;

  const int nf = in_sizes[0] / C_IN;   // 200000
  const int nv = in_sizes[3];          // 100000

  // ws: cnt[nv] | scale[128] | shift[128] | part[256*GB]
  //     | dwt[128*256 u16] | swt[256*32 u16] | slots[nv*CAP]
  //     | g[nf*128 u16] | pre[nv*128 u16]
  char* p = (char*)d_ws;
  int*    cnt   = (int*)p;            p += (size_t)nv * 4;
  float*  scale = (float*)p;          p += C_OUT * 4;
  float*  shift = (float*)p;          p += C_OUT * 4;
  float*  part  = (float*)p;          p += (size_t)256 * GB * 4;
  ushort* dwt   = (ushort*)p;         p += (size_t)C_OUT * CM * 2;
  ushort* swt   = (ushort*)p;         p += (size_t)CM * 32 * 2;
  int*    slots = (int*)p;            p += (size_t)nv * CAP * 4;
  ushort* g     = (ushort*)p;         p += (size_t)nf * C_OUT * 2;
  ushort* pre   = (ushort*)p;

  hipMemsetAsync(cnt, 0, (size_t)nv * 4, stream);

  const int n_inc = nf * 3;
  const int fill_blocks = (n_inc + 255) / 256;
  k_prepfill<<<96 + fill_blocks, 256, 0, stream>>>(dw, sw, dwt, swt,
                                                   face, vt_map, cnt, slots, n_inc);

  const int ntiles_f = (nf + FT - 1) / FT;   // 3125
  k_faceg<<<GRIDF, 256, 0, stream>>>(inputs, fc, swt, dwt, g, ntiles_f);

  const int ntiles_v = (nv + 15) / 16;       // 6250
  k_gather<<<GB, 256, 0, stream>>>(g, cnt, slots, nf_cnt, bias, pre, part, nv, ntiles_v);

  k_redfin<<<128, 256, 0, stream>>>(part, gamma, beta, scale, shift, 1.0f / (float)nv);

  const int n8 = (nv * C_OUT) / 8;           // 1.6M
  k_bn<<<2048, 256, 0, stream>>>(pre, scale, shift, out, n8);
}